// Round 5
// baseline (663.557 us; speedup 1.0000x reference)
//
#include <hip/hip_runtime.h>
#include <math.h>

typedef float vf4 __attribute__((ext_vector_type(4)));

// Bitonic network layer tables: l = blk*(blk+1)/2 + lay, m = 2^(blk-lay)
static constexpr int LLB[36] = {
  0,
  1,0,
  2,1,0,
  3,2,1,0,
  4,3,2,1,0,
  5,4,3,2,1,0,
  6,5,4,3,2,1,0,
  7,6,5,4,3,2,1,0
};
static constexpr int LBLK[36] = {
  0,
  1,1,
  2,2,2,
  3,3,3,3,
  4,4,4,4,4,
  5,5,5,5,5,5,
  6,6,6,6,6,6,6,
  7,7,7,7,7,7,7,7
};

// ---------------------------------------------------------------------------
// Kernel A: fused u-generation + blocks 0..5 (layers 0..20).  (R1-measured
// version, unchanged.)  u for layers 0..20 lives only in LDS; layers 21..35
// are written to global U2 (compact: 15*128 floats per batch) for kernel B.
// staged2 layout [b][g][t(16)][rr(64)] float4 -> both the store here and the
// load in kernel B are lane-contiguous 1KB per instruction.
// ---------------------------------------------------------------------------
__global__ __launch_bounds__(256) void k_gen1(const float* __restrict__ vec,
                                              float* __restrict__ U2,
                                              float4* __restrict__ staged2) {
  const int b = blockIdx.x;
  const int tid = threadIdx.x;
  __shared__ __align__(16) float ub[36 * 128];   // 18 KB
  __shared__ float vv[256];
  vv[tid] = vec[b * 256 + tid];
  __syncthreads();

  const int k = tid & 127;
  if (tid < 128) {
    #pragma unroll
    for (int l = 0; l < 18; ++l) {
      const int lb = LLB[l], blk = LBLK[l];
      const int m = 1 << lb;
      const int p = ((k >> lb) << (lb + 1)) | (k & (m - 1));
      const int q = p + m;
      const int d = (p >> (blk + 1)) & 1;
      const float alpha =
          atanf(10.0f * (vv[q] - vv[p])) * 0.3183098861837907f + 0.5f;
      ub[l * 128 + k] = d ? (1.0f - alpha) : alpha;
    }
  } else {
    #pragma unroll
    for (int l = 18; l < 36; ++l) {
      const int lb = LLB[l], blk = LBLK[l];
      const int m = 1 << lb;
      const int p = ((k >> lb) << (lb + 1)) | (k & (m - 1));
      const int q = p + m;
      const int d = (p >> (blk + 1)) & 1;
      const float alpha =
          atanf(10.0f * (vv[q] - vv[p])) * 0.3183098861837907f + 0.5f;
      const float u = d ? (1.0f - alpha) : alpha;
      ub[l * 128 + k] = u;
      if (l >= 21) U2[b * 1920 + (l - 21) * 128 + k] = u;
    }
  }
  __syncthreads();

  const int g  = tid >> 6;          // 64-col group (wave-uniform: wave == g)
  const int il = tid & 63;
  float r[64];
  #pragma unroll
  for (int j = 0; j < 64; ++j) r[j] = (j == il) ? 1.0f : 0.0f;

  #pragma unroll
  for (int l = 0; l < 21; ++l) {
    const int lb = LLB[l];
    const int m = 1 << lb;
    const float4* ulv = (const float4*)(ub + l * 128 + 32 * g);
    #pragma unroll
    for (int t = 0; t < 8; ++t) {
      const float4 u4 = ulv[t];     // ds_read_b128 broadcast (uniform addr)
      #pragma unroll
      for (int c = 0; c < 4; ++c) {
        const int kl = 4 * t + c;
        const int p = ((kl >> lb) << (lb + 1)) | (kl & (m - 1));
        const int q = p + m;
        const float u = (c == 0) ? u4.x : (c == 1) ? u4.y : (c == 2) ? u4.z : u4.w;
        const float t_  = r[p] - r[q];
        const float np = fmaf(u, t_, r[q]);
        const float nq = fmaf(-u, t_, r[p]);
        r[p] = np;
        r[q] = nq;
      }
    }
  }

  // coalesced store: per t, lanes il write 64 contiguous float4 (1KB)
  float4* sp = staged2 + ((size_t)(b * 4 + g) * 16) * 64 + il;
  #pragma unroll 4
  for (int t = 0; t < 16; ++t)
    sp[t * 64] = make_float4(r[4*t], r[4*t+1], r[4*t+2], r[4*t+3]);
}

// ---------------------------------------------------------------------------
// Kernel B: blocks 6..7 (layers 21..35).  (R1-measured structure.)
// Block = (b, rowgroup g of 64 rows), thread = (chunk c of 64 cols, row rr).
// LDS 32KB.  THIS ROUND'S ONLY CHANGE: __launch_bounds__(256,4) + partial
// (unroll 4) on the temp-heavy memory loops so live regs = y[64] + ~16 temps
// < 128 -> 4 waves/SIMD, 4 blocks/CU (was ~150 regs -> 2 waves/SIMD).
// ---------------------------------------------------------------------------
__global__ __launch_bounds__(256, 4) void k_phase23(const float* __restrict__ U2,
                                                    const float4* __restrict__ staged2,
                                                    float* __restrict__ out) {
  const int bg = blockIdx.x;
  const int b = bg >> 2;
  const int g = bg & 3;
  const int c  = threadIdx.x >> 6;      // chunk 0..3 (== wave id)
  const int rr = threadIdx.x & 63;      // row within group
  __shared__ float4 ex[2048];           // 32 KB
  float y[64];

  const int ub2 = __builtin_amdgcn_readfirstlane(b * 1920);
  const int ap = g >> 1;                // 128-region of this row group
  const bool part = ((c >> 1) == ap);   // wave-uniform: chunk holds nonzeros
  const int cb = __builtin_amdgcn_readfirstlane(32 * c);

  // ---- l=21 (blk6, m=64) + in-register layers 22..27 — nonzero chunks only
  if (part) {
    const bool sm = ((c & 1) == (g & 1));
    const float* u21 = U2 + ub2 + 64 * ap;          // layer 21 -> offset 0
    const float4* sp = staged2 + ((size_t)(b * 4 + g) * 16) * 64 + rr;
    #pragma unroll 4
    for (int t = 0; t < 16; ++t) {
      const float4 s4 = sp[t * 64];                 // lane-contiguous 1KB
      const float u0 = u21[4*t+0], u1 = u21[4*t+1];
      const float u2 = u21[4*t+2], u3 = u21[4*t+3];
      y[4*t+0] = s4.x * (sm ? u0 : 1.0f - u0);
      y[4*t+1] = s4.y * (sm ? u1 : 1.0f - u1);
      y[4*t+2] = s4.z * (sm ? u2 : 1.0f - u2);
      y[4*t+3] = s4.w * (sm ? u3 : 1.0f - u3);
    }
    #pragma unroll
    for (int l = 22; l < 28; ++l) {
      const int lb = LLB[l];
      const int m = 1 << lb;
      const float* ul = U2 + ub2 + (l - 21) * 128 + cb;
      #pragma unroll
      for (int kl = 0; kl < 32; ++kl) {
        const float u = ul[kl];
        const int p = ((kl >> lb) << (lb + 1)) | (kl & (m - 1));
        const int q = p + m;
        const float t_  = y[p] - y[q];
        const float np = fmaf(u, t_, y[q]);
        const float nq = fmaf(-u, t_, y[p]);
        y[p] = np;
        y[q] = nq;
      }
    }
  }

  // ---- l=28 (blk7, m=128): one side of each pair is zero.  Nonzero chunks
  // stage their values (2 chunks * 16 slots = 32KB exactly); they keep
  // y = u*y in-register; zero chunks read the partner and take (1-u)*p.
  {
    const float* u28 = U2 + ub2 + 7 * 128 + 64 * (c & 1);
    if (part) {
      #pragma unroll 4
      for (int t = 0; t < 16; ++t)
        ex[((c & 1) * 16 + t) * 64 + rr] =
            make_float4(y[4*t], y[4*t+1], y[4*t+2], y[4*t+3]);
    }
    __syncthreads();
    if (part) {
      #pragma unroll 4
      for (int t = 0; t < 16; ++t) {
        y[4*t+0] *= u28[4*t+0];
        y[4*t+1] *= u28[4*t+1];
        y[4*t+2] *= u28[4*t+2];
        y[4*t+3] *= u28[4*t+3];
      }
    } else {
      #pragma unroll 4
      for (int t = 0; t < 16; ++t) {
        const float4 p4 = ex[((c & 1) * 16 + t) * 64 + rr];  // partner c^2
        y[4*t+0] = fmaf(-u28[4*t+0], p4.x, p4.x);
        y[4*t+1] = fmaf(-u28[4*t+1], p4.y, p4.y);
        y[4*t+2] = fmaf(-u28[4*t+2], p4.z, p4.z);
        y[4*t+3] = fmaf(-u28[4*t+3], p4.w, p4.w);
      }
    }
    __syncthreads();
  }

  // ---- l=29 (blk7, m=64): full exchange with partner c^1, two 32KB halves
  {
    const float* u29 = U2 + ub2 + 8 * 128 + 64 * (c >> 1);
    const int pc = c ^ 1;
    // half A: t = 0..7
    #pragma unroll 4
    for (int t = 0; t < 8; ++t)
      ex[(c * 8 + t) * 64 + rr] =
          make_float4(y[4*t], y[4*t+1], y[4*t+2], y[4*t+3]);
    __syncthreads();
    #pragma unroll 4
    for (int t = 0; t < 8; ++t) {
      const float4 p4 = ex[(pc * 8 + t) * 64 + rr];
      y[4*t+0] = fmaf(u29[4*t+0], y[4*t+0] - p4.x, p4.x);
      y[4*t+1] = fmaf(u29[4*t+1], y[4*t+1] - p4.y, p4.y);
      y[4*t+2] = fmaf(u29[4*t+2], y[4*t+2] - p4.z, p4.z);
      y[4*t+3] = fmaf(u29[4*t+3], y[4*t+3] - p4.w, p4.w);
    }
    __syncthreads();
    // half B: t = 8..15
    #pragma unroll 4
    for (int t = 8; t < 16; ++t)
      ex[(c * 8 + (t - 8)) * 64 + rr] =
          make_float4(y[4*t], y[4*t+1], y[4*t+2], y[4*t+3]);
    __syncthreads();
    #pragma unroll 4
    for (int t = 8; t < 16; ++t) {
      const float4 p4 = ex[(pc * 8 + (t - 8)) * 64 + rr];
      y[4*t+0] = fmaf(u29[4*t+0], y[4*t+0] - p4.x, p4.x);
      y[4*t+1] = fmaf(u29[4*t+1], y[4*t+1] - p4.y, p4.y);
      y[4*t+2] = fmaf(u29[4*t+2], y[4*t+2] - p4.z, p4.z);
      y[4*t+3] = fmaf(u29[4*t+3], y[4*t+3] - p4.w, p4.w);
    }
    __syncthreads();
  }

  // ---- blk7 in-register layers l=30..35 (m=32..1)
  #pragma unroll
  for (int l = 30; l < 36; ++l) {
    const int lb = LLB[l];
    const int m = 1 << lb;
    const float* ul = U2 + ub2 + (l - 21) * 128 + cb;
    #pragma unroll
    for (int kl = 0; kl < 32; ++kl) {
      const float u = ul[kl];
      const int p = ((kl >> lb) << (lb + 1)) | (kl & (m - 1));
      const int q = p + m;
      const float t_  = y[p] - y[q];
      const float np = fmaf(u, t_, y[q]);
      const float nq = fmaf(-u, t_, y[p]);
      y[p] = np;
      y[q] = nq;
    }
  }

  // ---- XOR-swizzled LDS transpose -> coalesced 1KB/wave stores, in two
  // 32-row halves (32KB each).  Output region: rows [g*64, g*64+64) of b.
  float4* out4 = (float4*)out + ((size_t)(b * 256 + g * 64)) * 64;
  const int tid = threadIdx.x;

  if (rr < 32) {
    #pragma unroll 4
    for (int t = 0; t < 16; ++t)
      ex[rr * 64 + ((c * 16 + t) ^ (rr & 7))] =
          make_float4(y[4*t], y[4*t+1], y[4*t+2], y[4*t+3]);
  }
  __syncthreads();
  #pragma unroll 4
  for (int it = 0; it < 8; ++it) {
    const int fq = it * 256 + tid;
    const int rp = fq >> 6, q = fq & 63;
    const float4 v4 = ex[rp * 64 + (q ^ (rp & 7))];
    __builtin_nontemporal_store(*(const vf4*)&v4, (vf4*)&out4[rp * 64 + q]);
  }
  __syncthreads();
  if (rr >= 32) {
    #pragma unroll 4
    for (int t = 0; t < 16; ++t)
      ex[(rr - 32) * 64 + ((c * 16 + t) ^ (rr & 7))] =
          make_float4(y[4*t], y[4*t+1], y[4*t+2], y[4*t+3]);
  }
  __syncthreads();
  #pragma unroll 4
  for (int it = 0; it < 8; ++it) {
    const int fq = it * 256 + tid;
    const int rp = fq >> 6, q = fq & 63;
    const float4 v4 = ex[rp * 64 + (q ^ (rp & 7))];
    __builtin_nontemporal_store(*(const vf4*)&v4,
                                (vf4*)&out4[2048 + rp * 64 + q]);
  }
}

// ---------------------------------------------------------------------------
extern "C" void kernel_launch(void* const* d_in, const int* in_sizes, int n_in,
                              void* d_out, int out_size, void* d_ws, size_t ws_size,
                              hipStream_t stream) {
  const float* vec = (const float*)d_in[0];   // vectors (512,256) f32
  float* out = (float*)d_out;                 // (512,256,256) f32
  float* U2 = (float*)d_ws;                   // 512*1920 f32 = 3.93 MB (l 21..35)
  float* staged2 = U2 + (size_t)512 * 1920;   // 512*1024 float4 = 33.5 MB

  hipLaunchKernelGGL(k_gen1,    dim3(512),  dim3(256), 0, stream, vec, U2,
                     (float4*)staged2);
  hipLaunchKernelGGL(k_phase23, dim3(2048), dim3(256), 0, stream, U2,
                     (const float4*)staged2, out);
}

// Round 6
// 185.766 us; speedup vs baseline: 3.5720x; 3.5720x over previous
//
#include <hip/hip_runtime.h>
#include <math.h>

typedef float vf4 __attribute__((ext_vector_type(4)));

// Bitonic network layer tables: l = blk*(blk+1)/2 + lay, m = 2^(blk-lay)
static constexpr int LLB[36] = {
  0,
  1,0,
  2,1,0,
  3,2,1,0,
  4,3,2,1,0,
  5,4,3,2,1,0,
  6,5,4,3,2,1,0,
  7,6,5,4,3,2,1,0
};
static constexpr int LBLK[36] = {
  0,
  1,1,
  2,2,2,
  3,3,3,3,
  4,4,4,4,4,
  5,5,5,5,5,5,
  6,6,6,6,6,6,6,
  7,7,7,7,7,7,7,7
};

// ---------------------------------------------------------------------------
// Kernel A: fused u-generation + blocks 0..5 (layers 0..20).
// One block per batch b.  u for layers 0..20 lives only in LDS; layers
// 21..35 are written to global U2 (compact: 15*128 floats per batch) for
// kernel B.  Butterfly: thread = row, r[64] in registers (support of row i
// after blocks 0..5 is its 64-aligned column group).
// staged2 layout [b][g][t(16)][rr(64)] float4 -> both the store here and the
// load in kernel B are lane-contiguous 1KB per instruction.
// ---------------------------------------------------------------------------
__global__ __launch_bounds__(256) void k_gen1(const float* __restrict__ vec,
                                              float* __restrict__ U2,
                                              float4* __restrict__ staged2) {
  const int b = blockIdx.x;
  const int tid = threadIdx.x;
  __shared__ __align__(16) float ub[36 * 128];   // 18 KB
  __shared__ float vv[256];
  vv[tid] = vec[b * 256 + tid];
  __syncthreads();

  const int k = tid & 127;
  if (tid < 128) {
    #pragma unroll
    for (int l = 0; l < 18; ++l) {
      const int lb = LLB[l], blk = LBLK[l];
      const int m = 1 << lb;
      const int p = ((k >> lb) << (lb + 1)) | (k & (m - 1));
      const int q = p + m;
      const int d = (p >> (blk + 1)) & 1;
      const float alpha =
          atanf(10.0f * (vv[q] - vv[p])) * 0.3183098861837907f + 0.5f;
      ub[l * 128 + k] = d ? (1.0f - alpha) : alpha;
    }
  } else {
    #pragma unroll
    for (int l = 18; l < 36; ++l) {
      const int lb = LLB[l], blk = LBLK[l];
      const int m = 1 << lb;
      const int p = ((k >> lb) << (lb + 1)) | (k & (m - 1));
      const int q = p + m;
      const int d = (p >> (blk + 1)) & 1;
      const float alpha =
          atanf(10.0f * (vv[q] - vv[p])) * 0.3183098861837907f + 0.5f;
      const float u = d ? (1.0f - alpha) : alpha;
      ub[l * 128 + k] = u;
      if (l >= 21) U2[b * 1920 + (l - 21) * 128 + k] = u;
    }
  }
  __syncthreads();

  const int g  = tid >> 6;          // 64-col group (wave-uniform: wave == g)
  const int il = tid & 63;
  float r[64];
  #pragma unroll
  for (int j = 0; j < 64; ++j) r[j] = (j == il) ? 1.0f : 0.0f;

  #pragma unroll
  for (int l = 0; l < 21; ++l) {
    const int lb = LLB[l];
    const int m = 1 << lb;
    const float4* ulv = (const float4*)(ub + l * 128 + 32 * g);
    #pragma unroll
    for (int t = 0; t < 8; ++t) {
      const float4 u4 = ulv[t];     // ds_read_b128 broadcast (uniform addr)
      #pragma unroll
      for (int c = 0; c < 4; ++c) {
        const int kl = 4 * t + c;
        const int p = ((kl >> lb) << (lb + 1)) | (kl & (m - 1));
        const int q = p + m;
        const float u = (c == 0) ? u4.x : (c == 1) ? u4.y : (c == 2) ? u4.z : u4.w;
        const float t_  = r[p] - r[q];
        const float np = fmaf(u, t_, r[q]);
        const float nq = fmaf(-u, t_, r[p]);
        r[p] = np;
        r[q] = nq;
      }
    }
  }

  // coalesced store: per t, lanes il write 64 contiguous float4 (1KB)
  float4* sp = staged2 + ((size_t)(b * 4 + g) * 16) * 64 + il;
  #pragma unroll
  for (int t = 0; t < 16; ++t)
    sp[t * 64] = make_float4(r[4*t], r[4*t+1], r[4*t+2], r[4*t+3]);
}

// ---------------------------------------------------------------------------
// Kernel B: blocks 6..7 (layers 21..35).  Block = (b, rowgroup g of 64 rows),
// thread = (chunk c of 64 cols, row rr).  LDS 32KB: exchange-1 only stages
// the two nonzero chunks (32KB), exchange-2 and the output transpose run in
// two 32KB passes.  Dead work skipped: chunks outside the 128-region of g
// hold zeros through layer 27 -> they skip the staged load and layers 22..27
// entirely (wave-uniform branch), and exchange-1 degenerates to
// y=u*y / y=(1-u)*p.  NO launch_bounds reg-cap: R5 proved VGPR<=64 spills
// y[64] to scratch (8x write amplification, 3.4x regression).
// ---------------------------------------------------------------------------
__global__ __launch_bounds__(256) void k_phase23(const float* __restrict__ U2,
                                                 const float4* __restrict__ staged2,
                                                 float* __restrict__ out) {
  const int bg = blockIdx.x;
  const int b = bg >> 2;
  const int g = bg & 3;
  const int c  = threadIdx.x >> 6;      // chunk 0..3 (== wave id)
  const int rr = threadIdx.x & 63;      // row within group
  __shared__ float4 ex[2048];           // 32 KB
  float y[64];

  const int ub2 = __builtin_amdgcn_readfirstlane(b * 1920);
  const int ap = g >> 1;                // 128-region of this row group
  const bool part = ((c >> 1) == ap);   // wave-uniform: chunk holds nonzeros
  const int cb = __builtin_amdgcn_readfirstlane(32 * c);

  // ---- l=21 (blk6, m=64) + in-register layers 22..27 — nonzero chunks only
  if (part) {
    const bool sm = ((c & 1) == (g & 1));
    const float* u21 = U2 + ub2 + 64 * ap;          // layer 21 -> offset 0
    const float4* sp = staged2 + ((size_t)(b * 4 + g) * 16) * 64 + rr;
    #pragma unroll
    for (int t = 0; t < 16; ++t) {
      const float4 s4 = sp[t * 64];                 // lane-contiguous 1KB
      const float u0 = u21[4*t+0], u1 = u21[4*t+1];
      const float u2 = u21[4*t+2], u3 = u21[4*t+3];
      y[4*t+0] = s4.x * (sm ? u0 : 1.0f - u0);
      y[4*t+1] = s4.y * (sm ? u1 : 1.0f - u1);
      y[4*t+2] = s4.z * (sm ? u2 : 1.0f - u2);
      y[4*t+3] = s4.w * (sm ? u3 : 1.0f - u3);
    }
    #pragma unroll
    for (int l = 22; l < 28; ++l) {
      const int lb = LLB[l];
      const int m = 1 << lb;
      const float* ul = U2 + ub2 + (l - 21) * 128 + cb;
      #pragma unroll
      for (int kl = 0; kl < 32; ++kl) {
        const float u = ul[kl];
        const int p = ((kl >> lb) << (lb + 1)) | (kl & (m - 1));
        const int q = p + m;
        const float t_  = y[p] - y[q];
        const float np = fmaf(u, t_, y[q]);
        const float nq = fmaf(-u, t_, y[p]);
        y[p] = np;
        y[q] = nq;
      }
    }
  }

  // ---- l=28 (blk7, m=128): one side of each pair is zero.  Nonzero chunks
  // stage their values (2 chunks * 16 slots = 32KB exactly); they keep
  // y = u*y in-register; zero chunks read the partner and take (1-u)*p.
  {
    const float* u28 = U2 + ub2 + 7 * 128 + 64 * (c & 1);
    if (part) {
      #pragma unroll
      for (int t = 0; t < 16; ++t)
        ex[((c & 1) * 16 + t) * 64 + rr] =
            make_float4(y[4*t], y[4*t+1], y[4*t+2], y[4*t+3]);
    }
    __syncthreads();
    if (part) {
      #pragma unroll
      for (int t = 0; t < 16; ++t) {
        y[4*t+0] *= u28[4*t+0];
        y[4*t+1] *= u28[4*t+1];
        y[4*t+2] *= u28[4*t+2];
        y[4*t+3] *= u28[4*t+3];
      }
    } else {
      #pragma unroll
      for (int t = 0; t < 16; ++t) {
        const float4 p4 = ex[((c & 1) * 16 + t) * 64 + rr];  // partner c^2
        y[4*t+0] = fmaf(-u28[4*t+0], p4.x, p4.x);
        y[4*t+1] = fmaf(-u28[4*t+1], p4.y, p4.y);
        y[4*t+2] = fmaf(-u28[4*t+2], p4.z, p4.z);
        y[4*t+3] = fmaf(-u28[4*t+3], p4.w, p4.w);
      }
    }
    __syncthreads();
  }

  // ---- l=29 (blk7, m=64): full exchange with partner c^1, two 32KB halves
  {
    const float* u29 = U2 + ub2 + 8 * 128 + 64 * (c >> 1);
    const int pc = c ^ 1;
    // half A: t = 0..7
    #pragma unroll
    for (int t = 0; t < 8; ++t)
      ex[(c * 8 + t) * 64 + rr] =
          make_float4(y[4*t], y[4*t+1], y[4*t+2], y[4*t+3]);
    __syncthreads();
    #pragma unroll
    for (int t = 0; t < 8; ++t) {
      const float4 p4 = ex[(pc * 8 + t) * 64 + rr];
      y[4*t+0] = fmaf(u29[4*t+0], y[4*t+0] - p4.x, p4.x);
      y[4*t+1] = fmaf(u29[4*t+1], y[4*t+1] - p4.y, p4.y);
      y[4*t+2] = fmaf(u29[4*t+2], y[4*t+2] - p4.z, p4.z);
      y[4*t+3] = fmaf(u29[4*t+3], y[4*t+3] - p4.w, p4.w);
    }
    __syncthreads();
    // half B: t = 8..15
    #pragma unroll
    for (int t = 8; t < 16; ++t)
      ex[(c * 8 + (t - 8)) * 64 + rr] =
          make_float4(y[4*t], y[4*t+1], y[4*t+2], y[4*t+3]);
    __syncthreads();
    #pragma unroll
    for (int t = 8; t < 16; ++t) {
      const float4 p4 = ex[(pc * 8 + (t - 8)) * 64 + rr];
      y[4*t+0] = fmaf(u29[4*t+0], y[4*t+0] - p4.x, p4.x);
      y[4*t+1] = fmaf(u29[4*t+1], y[4*t+1] - p4.y, p4.y);
      y[4*t+2] = fmaf(u29[4*t+2], y[4*t+2] - p4.z, p4.z);
      y[4*t+3] = fmaf(u29[4*t+3], y[4*t+3] - p4.w, p4.w);
    }
    __syncthreads();
  }

  // ---- blk7 in-register layers l=30..35 (m=32..1)
  #pragma unroll
  for (int l = 30; l < 36; ++l) {
    const int lb = LLB[l];
    const int m = 1 << lb;
    const float* ul = U2 + ub2 + (l - 21) * 128 + cb;
    #pragma unroll
    for (int kl = 0; kl < 32; ++kl) {
      const float u = ul[kl];
      const int p = ((kl >> lb) << (lb + 1)) | (kl & (m - 1));
      const int q = p + m;
      const float t_  = y[p] - y[q];
      const float np = fmaf(u, t_, y[q]);
      const float nq = fmaf(-u, t_, y[p]);
      y[p] = np;
      y[q] = nq;
    }
  }

  // ---- XOR-swizzled LDS transpose -> coalesced 1KB/wave stores, in two
  // 32-row halves (32KB each).  Output region: rows [g*64, g*64+64) of b.
  float4* out4 = (float4*)out + ((size_t)(b * 256 + g * 64)) * 64;
  const int tid = threadIdx.x;

  if (rr < 32) {
    #pragma unroll
    for (int t = 0; t < 16; ++t)
      ex[rr * 64 + ((c * 16 + t) ^ (rr & 7))] =
          make_float4(y[4*t], y[4*t+1], y[4*t+2], y[4*t+3]);
  }
  __syncthreads();
  #pragma unroll
  for (int it = 0; it < 8; ++it) {
    const int fq = it * 256 + tid;
    const int rp = fq >> 6, q = fq & 63;
    const float4 v4 = ex[rp * 64 + (q ^ (rp & 7))];
    __builtin_nontemporal_store(*(const vf4*)&v4, (vf4*)&out4[rp * 64 + q]);
  }
  __syncthreads();
  if (rr >= 32) {
    #pragma unroll
    for (int t = 0; t < 16; ++t)
      ex[(rr - 32) * 64 + ((c * 16 + t) ^ (rr & 7))] =
          make_float4(y[4*t], y[4*t+1], y[4*t+2], y[4*t+3]);
  }
  __syncthreads();
  #pragma unroll
  for (int it = 0; it < 8; ++it) {
    const int fq = it * 256 + tid;
    const int rp = fq >> 6, q = fq & 63;
    const float4 v4 = ex[rp * 64 + (q ^ (rp & 7))];
    __builtin_nontemporal_store(*(const vf4*)&v4,
                                (vf4*)&out4[2048 + rp * 64 + q]);
  }
}

// ---------------------------------------------------------------------------
extern "C" void kernel_launch(void* const* d_in, const int* in_sizes, int n_in,
                              void* d_out, int out_size, void* d_ws, size_t ws_size,
                              hipStream_t stream) {
  const float* vec = (const float*)d_in[0];   // vectors (512,256) f32
  float* out = (float*)d_out;                 // (512,256,256) f32
  float* U2 = (float*)d_ws;                   // 512*1920 f32 = 3.93 MB (l 21..35)
  float* staged2 = U2 + (size_t)512 * 1920;   // 512*1024 float4 = 33.5 MB

  hipLaunchKernelGGL(k_gen1,    dim3(512),  dim3(256), 0, stream, vec, U2,
                     (float4*)staged2);
  hipLaunchKernelGGL(k_phase23, dim3(2048), dim3(256), 0, stream, U2,
                     (const float4*)staged2, out);
}